// Round 11
// baseline (120.060 us; speedup 1.0000x reference)
//
#include <hip/hip_runtime.h>

typedef float f32x4 __attribute__((ext_vector_type(4)));
typedef __bf16 bf16x8 __attribute__((ext_vector_type(8)));
typedef unsigned short u16x4 __attribute__((ext_vector_type(4)));
typedef unsigned short u16x8 __attribute__((ext_vector_type(8)));

constexpr int B_ = 2, A_ = 5, N_ = 1000, K_ = 16, F_ = 256, E_ = 3;
constexpr int RTOT = B_ * N_;            // 2000 valid rows (b,n)
constexpr int ROWS = 2016;               // padded to multiple of 32
constexpr int TIL  = 32;                 // rows per GEMM block
constexpr int NT   = ROWS / TIL;         // 63 tiles
constexpr int GBL  = NT * A_;            // 315 GEMM blocks
constexpr int KS1  = (E_ * F_) / 32;     // 24 k-steps, K=768
constexpr int KS2  = (2 * F_) / 32;      // 16 k-steps, K=512
constexpr int NTL  = F_ / 16;            // 16 col-tiles

constexpr int GATHER_BLOCKS = (A_ * ROWS) / 4;                       // 2520 (%8==0)
constexpr int PACK_THREADS  = A_ * KS1 * NTL * 64 + A_ * KS2 * NTL * 64;  // 204800
constexpr int PACK_BLOCKS   = PACK_THREADS / 256;                    // 800

// workspace layout (bytes) — ~24.2 MB
constexpr size_t SZ_WPK  = (size_t)A_ * KS1 * NTL * 512 * 2;   // 1,966,080
constexpr size_t OFF_W12 = SZ_WPK;
constexpr size_t SZ_W12  = (size_t)A_ * KS2 * NTL * 512 * 2;   // 1,310,720
constexpr size_t OFF_PWB = OFF_W12 + SZ_W12;
constexpr size_t SZ_PWB  = (size_t)A_ * ROWS * F_ * 2;         // 5,160,960
constexpr size_t OFF_SG  = OFF_PWB + SZ_PWB;
constexpr size_t SZ_SG   = (size_t)A_ * ROWS * (E_ * F_) * 2;  // 15,482,880
constexpr size_t OFF_CNT = OFF_SG + SZ_SG;                     // A*ROWS * f32x4
constexpr size_t SZ_CNT  = (size_t)A_ * ROWS * 16;             // 161,280
constexpr size_t OFF_FLG = OFF_CNT + SZ_CNT;                   // 63 x u32 tile flags

__device__ __forceinline__ unsigned short f2bf(float x) {
  unsigned int u = __builtin_bit_cast(unsigned int, x);
  u += 0x7fffu + ((u >> 16) & 1u);          // round-to-nearest-even
  return (unsigned short)(u >> 16);
}
__device__ __forceinline__ float bf2f(unsigned short h) {
  return __builtin_bit_cast(float, (unsigned int)h << 16);
}
// bijective XCD swizzle for 315 blocks: q=39, r=3 (m204 formula)
__device__ __forceinline__ int swz315(int bid) {
  const int xcd = bid & 7, idx = bid >> 3;
  return (xcd < 3 ? xcd * 40 : 120 + (xcd - 3) * 39) + idx;
}

// ---------------------------------------------------------------------------
// k_gather_pack: blocks [0,2520): one WARP per (a, padded-row) — a-major
// XCD chunking so each XCD works a contiguous row range of one 'a' (its 1MB
// nf slab stays L2-resident). blocks [2520,3320): pack W / [W1;W2] -> bf16
// MFMA B-fragment order.  (unchanged from round 10)
// ---------------------------------------------------------------------------
__global__ __launch_bounds__(256) void k_gather_pack(
    const float* __restrict__ nf, const int* __restrict__ nn_idx,
    const int* __restrict__ et, const float* __restrict__ W,
    const float* __restrict__ W1, const float* __restrict__ W2,
    unsigned short* __restrict__ Sg, float* __restrict__ CNTS,
    unsigned short* __restrict__ wpk, unsigned short* __restrict__ w12)
{
  if (blockIdx.x < GATHER_BLOCKS) {
    const int bid  = blockIdx.x;
    const int nbid = (bid & 7) * (GATHER_BLOCKS / 8) + (bid >> 3);  // XCD chunking
    const int task = nbid * 4 + (threadIdx.x >> 6);   // [0, A*ROWS)
    const int lane = threadIdx.x & 63;
    const int a  = task / ROWS;
    const int rp = task - a * ROWS;                   // padded row index
    const int rg = rp < RTOT ? rp : RTOT - 1;         // clamp pad -> dup last row
    const int bb = rg / N_;
    const int n  = rg - bb * N_;
    const int eoff = ((bb * A_ + a) * N_ + n) * K_;

    int4 iv[4], ev[4];
#pragma unroll
    for (int q = 0; q < 4; ++q) {
      iv[q] = *reinterpret_cast<const int4*>(nn_idx + eoff + q * 4);
      ev[q] = *reinterpret_cast<const int4*>(et + eoff + q * 4);
    }
    const float* __restrict__ slab =
        nf + (size_t)(bb * A_ + a) * N_ * F_ + lane * 4;
    f32x4 a0 = {0.f, 0.f, 0.f, 0.f}, a1 = a0, a2 = a0;
    int c0 = 0, c1 = 0, c2 = 0;
#pragma unroll
    for (int q = 0; q < 4; ++q) {
#pragma unroll
      for (int j = 0; j < 4; ++j) {
        const int id = ((const int*)&iv[q])[j];
        const int e  = ((const int*)&ev[q])[j];
        const f32x4 v = *reinterpret_cast<const f32x4*>(slab + (size_t)id * F_);
        if (e == 0)      { a0 += v; ++c0; }
        else if (e == 1) { a1 += v; ++c1; }
        else             { a2 += v; ++c2; }
      }
    }
    unsigned short* __restrict__ row = Sg + ((size_t)a * ROWS + rp) * 768;
    const int sw = (rp & 7) << 3;
    u16x4 p0, p1, p2;
#pragma unroll
    for (int j = 0; j < 4; ++j) {
      p0[j] = f2bf(a0[j]); p1[j] = f2bf(a1[j]); p2[j] = f2bf(a2[j]);
    }
    *reinterpret_cast<u16x4*>(row + ((0 * F_ + lane * 4) ^ sw)) = p0;
    *reinterpret_cast<u16x4*>(row + ((1 * F_ + lane * 4) ^ sw)) = p1;
    *reinterpret_cast<u16x4*>(row + ((2 * F_ + lane * 4) ^ sw)) = p2;
    if (lane == 0) {
      f32x4 c = {(float)c0, (float)c1, (float)c2, 0.f};
      *reinterpret_cast<f32x4*>(CNTS + (size_t)task * 4) = c;
    }
  } else {
    const int id = (blockIdx.x - GATHER_BLOCKS) * 256 + threadIdx.x;
    const int T1 = A_ * KS1 * NTL * 64;   // 122880
    const int T2 = A_ * KS2 * NTL * 64;   // 81920
    if (id < T1) {
      const int lane = id & 63, nt = (id >> 6) & 15;
      const int r = id >> 10, t = r % KS1, a = r / KS1;
      const int k0 = t * 32 + (lane >> 4) * 8;
      const int n  = nt * 16 + (lane & 15);
      const float* src = W + ((size_t)a * E_ * F_ + k0) * F_ + n;
      u16x8 v;
#pragma unroll
      for (int j = 0; j < 8; ++j) v[j] = f2bf(src[(size_t)j * F_]);
      *reinterpret_cast<u16x8*>(wpk + (size_t)id * 8) = v;
    } else if (id < T1 + T2) {
      const int p = id - T1;
      const int lane = p & 63, nt = (p >> 6) & 15;
      const int r = p >> 10, t = r % KS2, a = r / KS2;
      const int k0 = t * 32 + (lane >> 4) * 8;
      const int n  = nt * 16 + (lane & 15);
      u16x8 v;
#pragma unroll
      for (int j = 0; j < 8; ++j) {
        const int k = k0 + j;
        const float s = (k < F_) ? W1[((size_t)a * F_ + k) * F_ + n]
                                 : W2[((size_t)a * F_ + (k - F_)) * F_ + n];
        v[j] = f2bf(s);
      }
      *reinterpret_cast<u16x8*>(w12 + (size_t)p * 8) = v;
    }
  }
}

// ---------------------------------------------------------------------------
// k_gemm_hop: merged gemm1 + hop with per-tile producer-consumer flags.
// Block (tq,a) [tile-major over swz315 -> the 5 blocks of tile tq share an
// XCD chunk]:
//  phase A: stage Sg(a,tq) 48KB via global_load_lds; 8-wave MFMA GEMM
//           [32x768]x[768x256] -> bf16 pwb tile (hop swizzle pre-baked)
//  handoff: syncthreads (drain stores) -> threadfence (L2 wb) -> release
//           atomicAdd(flag[tq]); spin until flag[tq]==5 (acquire)
//  phase B: hop = relu([pw|mut] x [W1;W2] + b2) + nf -> out, with the 5
//           pwb tiles read L2-hot.
// Deadlock-free: 48.2KB LDS, 512 thr -> >=2 blocks/CU -> all 315 co-resident.
// ---------------------------------------------------------------------------
__global__ __launch_bounds__(512) void k_gemm_hop(
    const unsigned short* __restrict__ Sg, const float* __restrict__ CNTS,
    const unsigned short* __restrict__ wpk, const float* __restrict__ bias,
    unsigned short* __restrict__ pwb, const unsigned short* __restrict__ w12,
    const float* __restrict__ b2, const float* __restrict__ nf,
    float* __restrict__ out, unsigned* __restrict__ flags)
{
  __shared__ alignas(16) unsigned short S[TIL * E_ * F_];  // 48 KiB
  __shared__ float CNT[TIL][4];
  const int lin = swz315(blockIdx.x);
  const int tq  = lin / A_;            // tile index (tile-major)
  const int a   = lin - tq * A_;       // anchor
  const int r0  = tq * TIL;
  const int tid = threadIdx.x;
  const int lane = tid & 63, wv = tid >> 6;        // wv in [0,8)
  const int arow = lane & 15, kg = lane >> 4;
  const int ssw = (arow & 7) << 3;

  // ---- phase A: stage + GEMM1 ----
  {
    const unsigned short* src = Sg + ((size_t)a * ROWS + r0) * 768;
#pragma unroll
    for (int it = 0; it < 6; ++it) {
      const int off = (it * 512 + tid) * 8;   // shorts; 16 B per thread
      __builtin_amdgcn_global_load_lds(
          (const __attribute__((address_space(1))) unsigned int*)(src + off),
          (__attribute__((address_space(3))) unsigned int*)(S + off), 16, 0, 0);
    }
    if (tid < TIL)
      *reinterpret_cast<f32x4*>(&CNT[tid][0]) =
          *reinterpret_cast<const f32x4*>(CNTS + (size_t)(a * ROWS + r0 + tid) * 4);
    __syncthreads();

    const unsigned short* __restrict__ Wp = wpk + (size_t)a * KS1 * NTL * 512;
    f32x4 acc[2][2];
#pragma unroll
    for (int c = 0; c < 2; ++c)
#pragma unroll
      for (int mb = 0; mb < 2; ++mb) acc[c][mb] = (f32x4){0.f, 0.f, 0.f, 0.f};
#pragma unroll
    for (int t = 0; t < KS1; ++t) {
      bf16x8 af[2];
#pragma unroll
      for (int mb = 0; mb < 2; ++mb) {
        const int si = ((mb * 16 + arow) * 768 + t * 32 + kg * 8) ^ ssw;
        af[mb] = *reinterpret_cast<const bf16x8*>(&S[si]);
      }
#pragma unroll
      for (int c = 0; c < 2; ++c) {
        const int nt = wv * 2 + c;
        const bf16x8 bfr = *reinterpret_cast<const bf16x8*>(
            Wp + ((size_t)(t * NTL + nt) * 64 + lane) * 8);
#pragma unroll
        for (int mb = 0; mb < 2; ++mb)
          acc[c][mb] = __builtin_amdgcn_mfma_f32_16x16x32_bf16(af[mb], bfr, acc[c][mb], 0, 0, 0);
      }
    }

    const float* __restrict__ ba = bias + a * E_ * F_;
#pragma unroll
    for (int c = 0; c < 2; ++c) {
      const int col = (wv * 2 + c) * 16 + arow;
      const float b0 = ba[col], b1 = ba[F_ + col], b2v = ba[2 * F_ + col];
#pragma unroll
      for (int mb = 0; mb < 2; ++mb) {
#pragma unroll
        for (int rr = 0; rr < 4; ++rr) {
          const int row = mb * 16 + kg * 4 + rr;
          const int r   = r0 + row;
          float x = (acc[c][mb][rr] + CNT[row][0] * b0 + CNT[row][1] * b1 +
                     CNT[row][2] * b2v) * (1.0f / K_);
          x = fmaxf(x, 0.f);
          pwb[((size_t)a * ROWS + r) * F_ + (col ^ ((row & 7) << 3))] = f2bf(x);
        }
      }
    }
  }

  // ---- handoff: signal tile completion, wait for all 5 anchors ----
  __syncthreads();                       // drains vmcnt(0): all pwb stores issued+done
  if (tid == 0) {
    __threadfence();                     // agent-scope release (L2 writeback)
    __hip_atomic_fetch_add(flags + tq, 1u, __ATOMIC_RELEASE,
                           __HIP_MEMORY_SCOPE_AGENT);
    while (__hip_atomic_load(flags + tq, __ATOMIC_ACQUIRE,
                             __HIP_MEMORY_SCOPE_AGENT) < (unsigned)A_) {
      __builtin_amdgcn_s_sleep(2);
    }
  }
  __syncthreads();
  __threadfence();                       // acquire side: refetch below misses L1

  // ---- phase B: hop (reuse LDS: S2 = first 32 KiB of S) ----
  {
    unsigned short* S2 = S;
    const unsigned short* srcP = pwb + ((size_t)a * ROWS + r0) * F_;
#pragma unroll
    for (int it = 0; it < 2; ++it) {
      const int off = (it * 512 + tid) * 8;
      __builtin_amdgcn_global_load_lds(
          (const __attribute__((address_space(1))) unsigned int*)(srcP + off),
          (__attribute__((address_space(3))) unsigned int*)(S2 + off), 16, 0, 0);
    }
#pragma unroll
    for (int it = 0; it < 2; ++it) {
      const int i = (it * 512 + tid) * 8;
      float s[8] = {0.f, 0.f, 0.f, 0.f, 0.f, 0.f, 0.f, 0.f};
#pragma unroll
      for (int a2 = 0; a2 < A_; ++a2) {
        const u16x8 v = *reinterpret_cast<const u16x8*>(
            pwb + ((size_t)a2 * ROWS + r0) * F_ + i);
#pragma unroll
        for (int j = 0; j < 8; ++j) s[j] += bf2f(v[j]);
      }
      u16x8 o;
#pragma unroll
      for (int j = 0; j < 8; ++j) o[j] = f2bf(s[j]);
      *reinterpret_cast<u16x8*>(&S2[TIL * F_ + i]) = o;
    }
    __syncthreads();

    const unsigned short* __restrict__ Wp = w12 + (size_t)a * KS2 * NTL * 512;
    f32x4 acc[2][2];
#pragma unroll
    for (int c = 0; c < 2; ++c)
#pragma unroll
      for (int mb = 0; mb < 2; ++mb) acc[c][mb] = (f32x4){0.f, 0.f, 0.f, 0.f};
#pragma unroll
    for (int t = 0; t < KS2; ++t) {
      const int half = t >> 3;              // t<8: pw, t>=8: mutual
      const int kk   = (t & 7) * 32;
      bf16x8 af[2];
#pragma unroll
      for (int mb = 0; mb < 2; ++mb) {
        const int si = half * (TIL * F_) + (mb * 16 + arow) * F_ + ((kk + kg * 8) ^ ssw);
        af[mb] = *reinterpret_cast<const bf16x8*>(&S2[si]);
      }
#pragma unroll
      for (int c = 0; c < 2; ++c) {
        const int nt = wv * 2 + c;
        const bf16x8 bfr = *reinterpret_cast<const bf16x8*>(
            Wp + ((size_t)(t * NTL + nt) * 64 + lane) * 8);
#pragma unroll
        for (int mb = 0; mb < 2; ++mb)
          acc[c][mb] = __builtin_amdgcn_mfma_f32_16x16x32_bf16(af[mb], bfr, acc[c][mb], 0, 0, 0);
      }
    }

#pragma unroll
    for (int c = 0; c < 2; ++c) {
      const int col = (wv * 2 + c) * 16 + arow;
      const float bb2 = b2[a * F_ + col];
#pragma unroll
      for (int mb = 0; mb < 2; ++mb) {
#pragma unroll
        for (int rr = 0; rr < 4; ++rr) {
          const int row = mb * 16 + kg * 4 + rr;
          const int r   = r0 + row;
          if (r < RTOT) {
            const int bb = r / N_, n = r - bb * N_;
            const size_t o = ((size_t)(bb * A_ + a) * N_ + n) * F_ + col;
            out[o] = fmaxf(acc[c][mb][rr] + bb2, 0.f) + nf[o];
          }
        }
      }
    }
  }
}

// ---------------------------------------------------------------------------
extern "C" void kernel_launch(void* const* d_in, const int* in_sizes, int n_in,
                              void* d_out, int out_size, void* d_ws, size_t ws_size,
                              hipStream_t stream)
{
  const float* nf     = (const float*)d_in[0];
  const int*   nn_idx = (const int*)  d_in[1];
  const int*   et     = (const int*)  d_in[2];
  const float* W      = (const float*)d_in[3];
  const float* bias   = (const float*)d_in[4];
  const float* W1     = (const float*)d_in[5];
  const float* W2     = (const float*)d_in[6];
  const float* b2     = (const float*)d_in[7];
  float* out = (float*)d_out;

  unsigned short* wpk  = (unsigned short*)d_ws;
  unsigned short* w12  = (unsigned short*)((char*)d_ws + OFF_W12);
  unsigned short* pwb  = (unsigned short*)((char*)d_ws + OFF_PWB);
  unsigned short* Sg   = (unsigned short*)((char*)d_ws + OFF_SG);
  float*          CNTS = (float*)((char*)d_ws + OFF_CNT);
  unsigned*       flg  = (unsigned*)((char*)d_ws + OFF_FLG);

  // zero the 63 per-tile flags every call (graph-capturable, deterministic)
  hipMemsetAsync((void*)flg, 0, NT * sizeof(unsigned), stream);

  k_gather_pack<<<dim3(GATHER_BLOCKS + PACK_BLOCKS), 256, 0, stream>>>(
      nf, nn_idx, et, W, W1, W2, Sg, CNTS, wpk, w12);

  k_gemm_hop<<<dim3(GBL), 512, 0, stream>>>(
      Sg, CNTS, wpk, bias, pwb, w12, b2, nf, out, flg);
}

// Round 12
// 70.774 us; speedup vs baseline: 1.6964x; 1.6964x over previous
//
#include <hip/hip_runtime.h>

typedef float f32x4 __attribute__((ext_vector_type(4)));
typedef __bf16 bf16x8 __attribute__((ext_vector_type(8)));
typedef unsigned short u16x4 __attribute__((ext_vector_type(4)));
typedef unsigned short u16x8 __attribute__((ext_vector_type(8)));

constexpr int B_ = 2, A_ = 5, N_ = 1000, K_ = 16, F_ = 256, E_ = 3;
constexpr int RTOT = B_ * N_;            // 2000 valid rows (b,n)
constexpr int ROWS = 2016;               // padded to multiple of 32
constexpr int TIL  = 32;                 // rows per GEMM block
constexpr int NT   = ROWS / TIL;         // 63 tiles
constexpr int GBL  = NT * A_;            // 315 GEMM blocks
constexpr int KS1  = (E_ * F_) / 32;     // 24 k-steps, K=768
constexpr int KS2  = (2 * F_) / 32;      // 16 k-steps, K=512
constexpr int NTL  = F_ / 16;            // 16 col-tiles

constexpr int GATHER_BLOCKS = (A_ * ROWS) / 4;                       // 2520 (%8==0)
constexpr int PACK_THREADS  = A_ * KS1 * NTL * 64 + A_ * KS2 * NTL * 64;  // 204800
constexpr int PACK_BLOCKS   = PACK_THREADS / 256;                    // 800

// workspace layout (bytes) — ~24.2 MB
constexpr size_t SZ_WPK  = (size_t)A_ * KS1 * NTL * 512 * 2;   // 1,966,080
constexpr size_t OFF_W12 = SZ_WPK;
constexpr size_t SZ_W12  = (size_t)A_ * KS2 * NTL * 512 * 2;   // 1,310,720
constexpr size_t OFF_PWB = OFF_W12 + SZ_W12;
constexpr size_t SZ_PWB  = (size_t)A_ * ROWS * F_ * 2;         // 5,160,960
constexpr size_t OFF_SG  = OFF_PWB + SZ_PWB;
constexpr size_t SZ_SG   = (size_t)A_ * ROWS * (E_ * F_) * 2;  // 15,482,880
constexpr size_t OFF_CNT = OFF_SG + SZ_SG;                     // A*ROWS * f32x4
constexpr size_t SZ_CNT  = (size_t)A_ * ROWS * 16;             // 161,280
constexpr size_t OFF_FLG = OFF_CNT + SZ_CNT;                   // 63 x u32 tile flags

__device__ __forceinline__ unsigned short f2bf(float x) {
  unsigned int u = __builtin_bit_cast(unsigned int, x);
  u += 0x7fffu + ((u >> 16) & 1u);          // round-to-nearest-even
  return (unsigned short)(u >> 16);
}
__device__ __forceinline__ float bf2f(unsigned short h) {
  return __builtin_bit_cast(float, (unsigned int)h << 16);
}
// bijective XCD swizzle for 315 blocks: q=39, r=3 (m204 formula)
__device__ __forceinline__ int swz315(int bid) {
  const int xcd = bid & 7, idx = bid >> 3;
  return (xcd < 3 ? xcd * 40 : 120 + (xcd - 3) * 39) + idx;
}

// ---------------------------------------------------------------------------
// k_gather_pack: blocks [0,2520): one WARP per (a, padded-row) — a-major
// XCD chunking so each XCD works a contiguous row range of one 'a' (its 1MB
// nf slab stays L2-resident). blocks [2520,3320): pack W / [W1;W2] -> bf16
// MFMA B-fragment order.  (unchanged from round 10)
// ---------------------------------------------------------------------------
__global__ __launch_bounds__(256) void k_gather_pack(
    const float* __restrict__ nf, const int* __restrict__ nn_idx,
    const int* __restrict__ et, const float* __restrict__ W,
    const float* __restrict__ W1, const float* __restrict__ W2,
    unsigned short* __restrict__ Sg, float* __restrict__ CNTS,
    unsigned short* __restrict__ wpk, unsigned short* __restrict__ w12)
{
  if (blockIdx.x < GATHER_BLOCKS) {
    const int bid  = blockIdx.x;
    const int nbid = (bid & 7) * (GATHER_BLOCKS / 8) + (bid >> 3);  // XCD chunking
    const int task = nbid * 4 + (threadIdx.x >> 6);   // [0, A*ROWS)
    const int lane = threadIdx.x & 63;
    const int a  = task / ROWS;
    const int rp = task - a * ROWS;                   // padded row index
    const int rg = rp < RTOT ? rp : RTOT - 1;         // clamp pad -> dup last row
    const int bb = rg / N_;
    const int n  = rg - bb * N_;
    const int eoff = ((bb * A_ + a) * N_ + n) * K_;

    int4 iv[4], ev[4];
#pragma unroll
    for (int q = 0; q < 4; ++q) {
      iv[q] = *reinterpret_cast<const int4*>(nn_idx + eoff + q * 4);
      ev[q] = *reinterpret_cast<const int4*>(et + eoff + q * 4);
    }
    const float* __restrict__ slab =
        nf + (size_t)(bb * A_ + a) * N_ * F_ + lane * 4;
    f32x4 a0 = {0.f, 0.f, 0.f, 0.f}, a1 = a0, a2 = a0;
    int c0 = 0, c1 = 0, c2 = 0;
#pragma unroll
    for (int q = 0; q < 4; ++q) {
#pragma unroll
      for (int j = 0; j < 4; ++j) {
        const int id = ((const int*)&iv[q])[j];
        const int e  = ((const int*)&ev[q])[j];
        const f32x4 v = *reinterpret_cast<const f32x4*>(slab + (size_t)id * F_);
        if (e == 0)      { a0 += v; ++c0; }
        else if (e == 1) { a1 += v; ++c1; }
        else             { a2 += v; ++c2; }
      }
    }
    unsigned short* __restrict__ row = Sg + ((size_t)a * ROWS + rp) * 768;
    const int sw = (rp & 7) << 3;
    u16x4 p0, p1, p2;
#pragma unroll
    for (int j = 0; j < 4; ++j) {
      p0[j] = f2bf(a0[j]); p1[j] = f2bf(a1[j]); p2[j] = f2bf(a2[j]);
    }
    *reinterpret_cast<u16x4*>(row + ((0 * F_ + lane * 4) ^ sw)) = p0;
    *reinterpret_cast<u16x4*>(row + ((1 * F_ + lane * 4) ^ sw)) = p1;
    *reinterpret_cast<u16x4*>(row + ((2 * F_ + lane * 4) ^ sw)) = p2;
    if (lane == 0) {
      f32x4 c = {(float)c0, (float)c1, (float)c2, 0.f};
      *reinterpret_cast<f32x4*>(CNTS + (size_t)task * 4) = c;
    }
  } else {
    const int id = (blockIdx.x - GATHER_BLOCKS) * 256 + threadIdx.x;
    const int T1 = A_ * KS1 * NTL * 64;   // 122880
    const int T2 = A_ * KS2 * NTL * 64;   // 81920
    if (id < T1) {
      const int lane = id & 63, nt = (id >> 6) & 15;
      const int r = id >> 10, t = r % KS1, a = r / KS1;
      const int k0 = t * 32 + (lane >> 4) * 8;
      const int n  = nt * 16 + (lane & 15);
      const float* src = W + ((size_t)a * E_ * F_ + k0) * F_ + n;
      u16x8 v;
#pragma unroll
      for (int j = 0; j < 8; ++j) v[j] = f2bf(src[(size_t)j * F_]);
      *reinterpret_cast<u16x8*>(wpk + (size_t)id * 8) = v;
    } else if (id < T1 + T2) {
      const int p = id - T1;
      const int lane = p & 63, nt = (p >> 6) & 15;
      const int r = p >> 10, t = r % KS2, a = r / KS2;
      const int k0 = t * 32 + (lane >> 4) * 8;
      const int n  = nt * 16 + (lane & 15);
      u16x8 v;
#pragma unroll
      for (int j = 0; j < 8; ++j) {
        const int k = k0 + j;
        const float s = (k < F_) ? W1[((size_t)a * F_ + k) * F_ + n]
                                 : W2[((size_t)a * F_ + (k - F_)) * F_ + n];
        v[j] = f2bf(s);
      }
      *reinterpret_cast<u16x8*>(w12 + (size_t)p * 8) = v;
    }
  }
}

// ---------------------------------------------------------------------------
// k_gemm_hop: merged gemm1 + hop with per-tile producer-consumer flags.
// Handoff protocol (fixed vs round 11):
//  - __syncthreads drains vmcnt -> all pwb stores complete
//  - thread 0 ONLY: release atomicAdd (compiler emits L2 writeback), RELAXED
//    spin, then ONE __threadfence (L1+L2 invalidate — cache-wide ops, so one
//    per block suffices; the block lives on one CU)
//  - __syncthreads publishes to the rest of the block
// Round 11's bug: all 512 threads executed the acquire __threadfence ->
// 512 L2-writeback/invalidate ops per block = fabric storm (95us of stall).
// ---------------------------------------------------------------------------
__global__ __launch_bounds__(512) void k_gemm_hop(
    const unsigned short* __restrict__ Sg, const float* __restrict__ CNTS,
    const unsigned short* __restrict__ wpk, const float* __restrict__ bias,
    unsigned short* __restrict__ pwb, const unsigned short* __restrict__ w12,
    const float* __restrict__ b2, const float* __restrict__ nf,
    float* __restrict__ out, unsigned* __restrict__ flags)
{
  __shared__ alignas(16) unsigned short S[TIL * E_ * F_];  // 48 KiB
  __shared__ float CNT[TIL][4];
  const int lin = swz315(blockIdx.x);
  const int tq  = lin / A_;            // tile index (tile-major)
  const int a   = lin - tq * A_;       // anchor
  const int r0  = tq * TIL;
  const int tid = threadIdx.x;
  const int lane = tid & 63, wv = tid >> 6;        // wv in [0,8)
  const int arow = lane & 15, kg = lane >> 4;
  const int ssw = (arow & 7) << 3;

  // ---- phase A: stage + GEMM1 ----
  {
    const unsigned short* src = Sg + ((size_t)a * ROWS + r0) * 768;
#pragma unroll
    for (int it = 0; it < 6; ++it) {
      const int off = (it * 512 + tid) * 8;   // shorts; 16 B per thread
      __builtin_amdgcn_global_load_lds(
          (const __attribute__((address_space(1))) unsigned int*)(src + off),
          (__attribute__((address_space(3))) unsigned int*)(S + off), 16, 0, 0);
    }
    if (tid < TIL)
      *reinterpret_cast<f32x4*>(&CNT[tid][0]) =
          *reinterpret_cast<const f32x4*>(CNTS + (size_t)(a * ROWS + r0 + tid) * 4);
    __syncthreads();

    const unsigned short* __restrict__ Wp = wpk + (size_t)a * KS1 * NTL * 512;
    f32x4 acc[2][2];
#pragma unroll
    for (int c = 0; c < 2; ++c)
#pragma unroll
      for (int mb = 0; mb < 2; ++mb) acc[c][mb] = (f32x4){0.f, 0.f, 0.f, 0.f};
#pragma unroll
    for (int t = 0; t < KS1; ++t) {
      bf16x8 af[2];
#pragma unroll
      for (int mb = 0; mb < 2; ++mb) {
        const int si = ((mb * 16 + arow) * 768 + t * 32 + kg * 8) ^ ssw;
        af[mb] = *reinterpret_cast<const bf16x8*>(&S[si]);
      }
#pragma unroll
      for (int c = 0; c < 2; ++c) {
        const int nt = wv * 2 + c;
        const bf16x8 bfr = *reinterpret_cast<const bf16x8*>(
            Wp + ((size_t)(t * NTL + nt) * 64 + lane) * 8);
#pragma unroll
        for (int mb = 0; mb < 2; ++mb)
          acc[c][mb] = __builtin_amdgcn_mfma_f32_16x16x32_bf16(af[mb], bfr, acc[c][mb], 0, 0, 0);
      }
    }

    const float* __restrict__ ba = bias + a * E_ * F_;
#pragma unroll
    for (int c = 0; c < 2; ++c) {
      const int col = (wv * 2 + c) * 16 + arow;
      const float b0 = ba[col], b1 = ba[F_ + col], b2v = ba[2 * F_ + col];
#pragma unroll
      for (int mb = 0; mb < 2; ++mb) {
#pragma unroll
        for (int rr = 0; rr < 4; ++rr) {
          const int row = mb * 16 + kg * 4 + rr;
          const int r   = r0 + row;
          float x = (acc[c][mb][rr] + CNT[row][0] * b0 + CNT[row][1] * b1 +
                     CNT[row][2] * b2v) * (1.0f / K_);
          x = fmaxf(x, 0.f);
          pwb[((size_t)a * ROWS + r) * F_ + (col ^ ((row & 7) << 3))] = f2bf(x);
        }
      }
    }
  }

  // ---- handoff: thread-0-only release/spin/acquire ----
  __syncthreads();                       // drains vmcnt(0): pwb stores complete
  if (tid == 0) {
    __hip_atomic_fetch_add(flags + tq, 1u, __ATOMIC_RELEASE,
                           __HIP_MEMORY_SCOPE_AGENT);      // release: L2 wb + add
    while (__hip_atomic_load(flags + tq, __ATOMIC_RELAXED,
                             __HIP_MEMORY_SCOPE_AGENT) < (unsigned)A_) {
      __builtin_amdgcn_s_sleep(8);
    }
    __threadfence();                     // ONE acquire fence: inv L1 (this CU) + L2
  }
  __syncthreads();                       // publish to whole block

  // ---- phase B: hop (reuse LDS: S2 = first 32 KiB of S) ----
  {
    unsigned short* S2 = S;
    const unsigned short* srcP = pwb + ((size_t)a * ROWS + r0) * F_;
#pragma unroll
    for (int it = 0; it < 2; ++it) {
      const int off = (it * 512 + tid) * 8;
      __builtin_amdgcn_global_load_lds(
          (const __attribute__((address_space(1))) unsigned int*)(srcP + off),
          (__attribute__((address_space(3))) unsigned int*)(S2 + off), 16, 0, 0);
    }
#pragma unroll
    for (int it = 0; it < 2; ++it) {
      const int i = (it * 512 + tid) * 8;
      float s[8] = {0.f, 0.f, 0.f, 0.f, 0.f, 0.f, 0.f, 0.f};
#pragma unroll
      for (int a2 = 0; a2 < A_; ++a2) {
        const u16x8 v = *reinterpret_cast<const u16x8*>(
            pwb + ((size_t)a2 * ROWS + r0) * F_ + i);
#pragma unroll
        for (int j = 0; j < 8; ++j) s[j] += bf2f(v[j]);
      }
      u16x8 o;
#pragma unroll
      for (int j = 0; j < 8; ++j) o[j] = f2bf(s[j]);
      *reinterpret_cast<u16x8*>(&S2[TIL * F_ + i]) = o;
    }
    __syncthreads();

    const unsigned short* __restrict__ Wp = w12 + (size_t)a * KS2 * NTL * 512;
    f32x4 acc[2][2];
#pragma unroll
    for (int c = 0; c < 2; ++c)
#pragma unroll
      for (int mb = 0; mb < 2; ++mb) acc[c][mb] = (f32x4){0.f, 0.f, 0.f, 0.f};
#pragma unroll
    for (int t = 0; t < KS2; ++t) {
      const int half = t >> 3;              // t<8: pw, t>=8: mutual
      const int kk   = (t & 7) * 32;
      bf16x8 af[2];
#pragma unroll
      for (int mb = 0; mb < 2; ++mb) {
        const int si = half * (TIL * F_) + (mb * 16 + arow) * F_ + ((kk + kg * 8) ^ ssw);
        af[mb] = *reinterpret_cast<const bf16x8*>(&S2[si]);
      }
#pragma unroll
      for (int c = 0; c < 2; ++c) {
        const int nt = wv * 2 + c;
        const bf16x8 bfr = *reinterpret_cast<const bf16x8*>(
            Wp + ((size_t)(t * NTL + nt) * 64 + lane) * 8);
#pragma unroll
        for (int mb = 0; mb < 2; ++mb)
          acc[c][mb] = __builtin_amdgcn_mfma_f32_16x16x32_bf16(af[mb], bfr, acc[c][mb], 0, 0, 0);
      }
    }

#pragma unroll
    for (int c = 0; c < 2; ++c) {
      const int col = (wv * 2 + c) * 16 + arow;
      const float bb2 = b2[a * F_ + col];
#pragma unroll
      for (int mb = 0; mb < 2; ++mb) {
#pragma unroll
        for (int rr = 0; rr < 4; ++rr) {
          const int row = mb * 16 + kg * 4 + rr;
          const int r   = r0 + row;
          if (r < RTOT) {
            const int bb = r / N_, n = r - bb * N_;
            const size_t o = ((size_t)(bb * A_ + a) * N_ + n) * F_ + col;
            out[o] = fmaxf(acc[c][mb][rr] + bb2, 0.f) + nf[o];
          }
        }
      }
    }
  }
}

// ---------------------------------------------------------------------------
extern "C" void kernel_launch(void* const* d_in, const int* in_sizes, int n_in,
                              void* d_out, int out_size, void* d_ws, size_t ws_size,
                              hipStream_t stream)
{
  const float* nf     = (const float*)d_in[0];
  const int*   nn_idx = (const int*)  d_in[1];
  const int*   et     = (const int*)  d_in[2];
  const float* W      = (const float*)d_in[3];
  const float* bias   = (const float*)d_in[4];
  const float* W1     = (const float*)d_in[5];
  const float* W2     = (const float*)d_in[6];
  const float* b2     = (const float*)d_in[7];
  float* out = (float*)d_out;

  unsigned short* wpk  = (unsigned short*)d_ws;
  unsigned short* w12  = (unsigned short*)((char*)d_ws + OFF_W12);
  unsigned short* pwb  = (unsigned short*)((char*)d_ws + OFF_PWB);
  unsigned short* Sg   = (unsigned short*)((char*)d_ws + OFF_SG);
  float*          CNTS = (float*)((char*)d_ws + OFF_CNT);
  unsigned*       flg  = (unsigned*)((char*)d_ws + OFF_FLG);

  // zero the 63 per-tile flags every call (graph-capturable, deterministic)
  hipMemsetAsync((void*)flg, 0, NT * sizeof(unsigned), stream);

  k_gather_pack<<<dim3(GATHER_BLOCKS + PACK_BLOCKS), 256, 0, stream>>>(
      nf, nn_idx, et, W, W1, W2, Sg, CNTS, wpk, w12);

  k_gemm_hop<<<dim3(GBL), 512, 0, stream>>>(
      Sg, CNTS, wpk, bias, pwb, w12, b2, nf, out, flg);
}

// Round 13
// 45.963 us; speedup vs baseline: 2.6121x; 1.5398x over previous
//
#include <hip/hip_runtime.h>

typedef float f32x4 __attribute__((ext_vector_type(4)));
typedef __bf16 bf16x8 __attribute__((ext_vector_type(8)));
typedef unsigned short u16x4 __attribute__((ext_vector_type(4)));
typedef unsigned short u16x8 __attribute__((ext_vector_type(8)));

constexpr int B_ = 2, A_ = 5, N_ = 1000, K_ = 16, F_ = 256, E_ = 3;
constexpr int RTOT = B_ * N_;            // 2000 valid rows (b,n)
constexpr int ROWS = 2016;               // padded to multiple of 32
constexpr int TIL  = 32;                 // rows per GEMM block
constexpr int NT   = ROWS / TIL;         // 63 tiles
constexpr int GBL  = NT * A_;            // 315 GEMM blocks
constexpr int KS1  = (E_ * F_) / 32;     // 24 k-steps, K=768
constexpr int KS2  = (2 * F_) / 32;      // 16 k-steps, K=512
constexpr int NTL  = F_ / 16;            // 16 col-tiles

constexpr int GATHER_BLOCKS = (A_ * ROWS) / 4;                       // 2520 (%8==0)
constexpr int PACK_THREADS  = A_ * KS1 * NTL * 64 + A_ * KS2 * NTL * 64;  // 204800
constexpr int PACK_BLOCKS   = PACK_THREADS / 256;                    // 800

// workspace layout (bytes) — ~24.1 MB
constexpr size_t SZ_WPK  = (size_t)A_ * KS1 * NTL * 512 * 2;   // 1,966,080
constexpr size_t OFF_W12 = SZ_WPK;
constexpr size_t SZ_W12  = (size_t)A_ * KS2 * NTL * 512 * 2;   // 1,310,720
constexpr size_t OFF_PWB = OFF_W12 + SZ_W12;
constexpr size_t SZ_PWB  = (size_t)A_ * ROWS * F_ * 2;         // 5,160,960
constexpr size_t OFF_SG  = OFF_PWB + SZ_PWB;
constexpr size_t SZ_SG   = (size_t)A_ * ROWS * (E_ * F_) * 2;  // 15,482,880
constexpr size_t OFF_CNT = OFF_SG + SZ_SG;                     // A*ROWS * f32x4

__device__ __forceinline__ unsigned short f2bf(float x) {
  unsigned int u = __builtin_bit_cast(unsigned int, x);
  u += 0x7fffu + ((u >> 16) & 1u);          // round-to-nearest-even
  return (unsigned short)(u >> 16);
}
__device__ __forceinline__ float bf2f(unsigned short h) {
  return __builtin_bit_cast(float, (unsigned int)h << 16);
}
// bijective XCD swizzle for 315 blocks: q=39, r=3 (m204 formula)
__device__ __forceinline__ int swz315(int bid) {
  const int xcd = bid & 7, idx = bid >> 3;
  return (xcd < 3 ? xcd * 40 : 120 + (xcd - 3) * 39) + idx;
}

// ---------------------------------------------------------------------------
// k_gather_pack: blocks [0,2520): one WARP per (a, padded-row) — a-major XCD
// chunking (nf slab stays L2-resident). NEW vs round 10: neighbor indices and
// edge types are readfirstlane'd into SGPRs (they are wave-uniform), so the
// bucket selection becomes scalar-branched (plain v_add x4 per neighbor
// instead of ~27 cndmask/cmp VALU ops) and gather addresses use SGPR base +
// constant per-lane offset. Bucket0 = total - b1 - b2.
// blocks [2520,3320): pack W / [W1;W2] -> bf16 MFMA B-fragment order.
// ---------------------------------------------------------------------------
__global__ __launch_bounds__(256) void k_gather_pack(
    const float* __restrict__ nf, const int* __restrict__ nn_idx,
    const int* __restrict__ et, const float* __restrict__ W,
    const float* __restrict__ W1, const float* __restrict__ W2,
    unsigned short* __restrict__ Sg, float* __restrict__ CNTS,
    unsigned short* __restrict__ wpk, unsigned short* __restrict__ w12)
{
  if (blockIdx.x < GATHER_BLOCKS) {
    const int bid  = blockIdx.x;
    const int nbid = (bid & 7) * (GATHER_BLOCKS / 8) + (bid >> 3);  // XCD chunking
    const int task = nbid * 4 + (threadIdx.x >> 6);   // [0, A*ROWS)
    const int lane = threadIdx.x & 63;
    const int a  = task / ROWS;
    const int rp = task - a * ROWS;                   // padded row index
    const int rg = rp < RTOT ? rp : RTOT - 1;         // clamp pad -> dup last row
    const int bb = rg / N_;
    const int n  = rg - bb * N_;
    const int eoff = ((bb * A_ + a) * N_ + n) * K_;

    // vector-load idx/etype, then hoist to SGPRs (wave-uniform values)
    int4 iv[4], ev[4];
#pragma unroll
    for (int q = 0; q < 4; ++q) {
      iv[q] = *reinterpret_cast<const int4*>(nn_idx + eoff + q * 4);
      ev[q] = *reinterpret_cast<const int4*>(et + eoff + q * 4);
    }
    int ids[16], es[16];
#pragma unroll
    for (int q = 0; q < 4; ++q) {
#pragma unroll
      for (int j = 0; j < 4; ++j) {
        ids[q * 4 + j] = __builtin_amdgcn_readfirstlane(((const int*)&iv[q])[j]);
        es[q * 4 + j]  = __builtin_amdgcn_readfirstlane(((const int*)&ev[q])[j]);
      }
    }

    const float* __restrict__ slab =
        nf + (size_t)(bb * A_ + a) * N_ * F_ + lane * 4;
    f32x4 at = {0.f, 0.f, 0.f, 0.f}, a1 = at, a2 = at;   // total, bucket1, bucket2
    int c1 = 0, c2 = 0;
#pragma unroll
    for (int k = 0; k < K_; ++k) {
      const f32x4 v = *reinterpret_cast<const f32x4*>(slab + (size_t)ids[k] * F_);
      at += v;                                  // always
      const int e = es[k];                      // SGPR -> uniform branch
      if (e == 1)      { a1 += v; ++c1; }
      else if (e == 2) { a2 += v; ++c2; }
    }
    const f32x4 a0 = at - a1 - a2;
    const int   c0 = K_ - c1 - c2;

    unsigned short* __restrict__ row = Sg + ((size_t)a * ROWS + rp) * 768;
    const int sw = (rp & 7) << 3;
    u16x4 p0, p1, p2;
#pragma unroll
    for (int j = 0; j < 4; ++j) {
      p0[j] = f2bf(a0[j]); p1[j] = f2bf(a1[j]); p2[j] = f2bf(a2[j]);
    }
    *reinterpret_cast<u16x4*>(row + ((0 * F_ + lane * 4) ^ sw)) = p0;
    *reinterpret_cast<u16x4*>(row + ((1 * F_ + lane * 4) ^ sw)) = p1;
    *reinterpret_cast<u16x4*>(row + ((2 * F_ + lane * 4) ^ sw)) = p2;
    if (lane == 0) {
      f32x4 c = {(float)c0, (float)c1, (float)c2, 0.f};
      *reinterpret_cast<f32x4*>(CNTS + (size_t)task * 4) = c;
    }
  } else {
    const int id = (blockIdx.x - GATHER_BLOCKS) * 256 + threadIdx.x;
    const int T1 = A_ * KS1 * NTL * 64;   // 122880
    const int T2 = A_ * KS2 * NTL * 64;   // 81920
    if (id < T1) {
      const int lane = id & 63, nt = (id >> 6) & 15;
      const int r = id >> 10, t = r % KS1, a = r / KS1;
      const int k0 = t * 32 + (lane >> 4) * 8;
      const int n  = nt * 16 + (lane & 15);
      const float* src = W + ((size_t)a * E_ * F_ + k0) * F_ + n;
      u16x8 v;
#pragma unroll
      for (int j = 0; j < 8; ++j) v[j] = f2bf(src[(size_t)j * F_]);
      *reinterpret_cast<u16x8*>(wpk + (size_t)id * 8) = v;
    } else if (id < T1 + T2) {
      const int p = id - T1;
      const int lane = p & 63, nt = (p >> 6) & 15;
      const int r = p >> 10, t = r % KS2, a = r / KS2;
      const int k0 = t * 32 + (lane >> 4) * 8;
      const int n  = nt * 16 + (lane & 15);
      u16x8 v;
#pragma unroll
      for (int j = 0; j < 8; ++j) {
        const int k = k0 + j;
        const float s = (k < F_) ? W1[((size_t)a * F_ + k) * F_ + n]
                                 : W2[((size_t)a * F_ + (k - F_)) * F_ + n];
        v[j] = f2bf(s);
      }
      *reinterpret_cast<u16x8*>(w12 + (size_t)p * 8) = v;
    }
  }
}

// ---------------------------------------------------------------------------
// k_gemm1: TILE=32, 512 threads (8 waves). Stage 48 KB Sg tile via
// global_load_lds; wave = 2 col-tiles x 2 m-blocks. -> bf16 pwb (hop swizzle).
// (verbatim round 10)
// ---------------------------------------------------------------------------
__global__ __launch_bounds__(512) void k_gemm1(
    const unsigned short* __restrict__ Sg, const float* __restrict__ CNTS,
    const unsigned short* __restrict__ wpk, const float* __restrict__ bias,
    unsigned short* __restrict__ pwb)
{
  __shared__ alignas(16) unsigned short S[TIL * E_ * F_];  // 48 KiB
  __shared__ float CNT[TIL][4];
  const int lin = swz315(blockIdx.x);
  const int tq  = lin / A_;            // tile index  (tile-major)
  const int a   = lin - tq * A_;       // anchor
  const int r0  = tq * TIL;
  const int tid = threadIdx.x;

  const unsigned short* src = Sg + ((size_t)a * ROWS + r0) * 768;
#pragma unroll
  for (int it = 0; it < 6; ++it) {
    const int off = (it * 512 + tid) * 8;   // shorts; 16 B per thread
    __builtin_amdgcn_global_load_lds(
        (const __attribute__((address_space(1))) unsigned int*)(src + off),
        (__attribute__((address_space(3))) unsigned int*)(S + off), 16, 0, 0);
  }
  if (tid < TIL)
    *reinterpret_cast<f32x4*>(&CNT[tid][0]) =
        *reinterpret_cast<const f32x4*>(CNTS + (size_t)(a * ROWS + r0 + tid) * 4);
  __syncthreads();

  const int lane = tid & 63, wv = tid >> 6;        // wv in [0,8)
  const int arow = lane & 15, kg = lane >> 4;
  const unsigned short* __restrict__ Wp = wpk + (size_t)a * KS1 * NTL * 512;
  f32x4 acc[2][2];
#pragma unroll
  for (int c = 0; c < 2; ++c)
#pragma unroll
    for (int mb = 0; mb < 2; ++mb) acc[c][mb] = (f32x4){0.f, 0.f, 0.f, 0.f};
  const int ssw = (arow & 7) << 3;
#pragma unroll
  for (int t = 0; t < KS1; ++t) {
    bf16x8 af[2];
#pragma unroll
    for (int mb = 0; mb < 2; ++mb) {
      const int si = ((mb * 16 + arow) * 768 + t * 32 + kg * 8) ^ ssw;
      af[mb] = *reinterpret_cast<const bf16x8*>(&S[si]);
    }
#pragma unroll
    for (int c = 0; c < 2; ++c) {
      const int nt = wv * 2 + c;
      const bf16x8 bfr = *reinterpret_cast<const bf16x8*>(
          Wp + ((size_t)(t * NTL + nt) * 64 + lane) * 8);
#pragma unroll
      for (int mb = 0; mb < 2; ++mb)
        acc[c][mb] = __builtin_amdgcn_mfma_f32_16x16x32_bf16(af[mb], bfr, acc[c][mb], 0, 0, 0);
    }
  }

  const float* __restrict__ ba = bias + a * E_ * F_;
#pragma unroll
  for (int c = 0; c < 2; ++c) {
    const int col = (wv * 2 + c) * 16 + arow;
    const float b0 = ba[col], b1 = ba[F_ + col], b2v = ba[2 * F_ + col];
#pragma unroll
    for (int mb = 0; mb < 2; ++mb) {
#pragma unroll
      for (int rr = 0; rr < 4; ++rr) {
        const int row = mb * 16 + kg * 4 + rr;
        const int r   = r0 + row;
        float x = (acc[c][mb][rr] + CNT[row][0] * b0 + CNT[row][1] * b1 +
                   CNT[row][2] * b2v) * (1.0f / K_);
        x = fmaxf(x, 0.f);
        pwb[((size_t)a * ROWS + r) * F_ + (col ^ ((row & 7) << 3))] = f2bf(x);
      }
    }
  }
}

// ---------------------------------------------------------------------------
// k_hop_mfma: out = relu([pw | mut] x [W1;W2] + b2) + nf. TILE=32, 512 thr.
// P staged via global_load_lds (pre-swizzled); mutual computed in-flight.
// (verbatim round 10)
// ---------------------------------------------------------------------------
__global__ __launch_bounds__(512) void k_hop_mfma(
    const unsigned short* __restrict__ pwb, const unsigned short* __restrict__ w12,
    const float* __restrict__ b2, const float* __restrict__ nf,
    float* __restrict__ out)
{
  __shared__ alignas(16) unsigned short S2[2 * TIL * F_];  // 32 KiB
  const int lin = swz315(blockIdx.x);
  const int tq  = lin / A_;            // tile index (tile-major, matches gemm1)
  const int a   = lin - tq * A_;
  const int r0  = tq * TIL;
  const int tid = threadIdx.x;

  // P half: 16 KB linear copy (layout already swizzled per row)
  const unsigned short* srcP = pwb + ((size_t)a * ROWS + r0) * F_;
#pragma unroll
  for (int it = 0; it < 2; ++it) {
    const int off = (it * 512 + tid) * 8;
    __builtin_amdgcn_global_load_lds(
        (const __attribute__((address_space(1))) unsigned int*)(srcP + off),
        (__attribute__((address_space(3))) unsigned int*)(S2 + off), 16, 0, 0);
  }
  // M half: mutual = sum over a2 (element-wise; same per-row swizzle)
#pragma unroll
  for (int it = 0; it < 2; ++it) {
    const int i = (it * 512 + tid) * 8;
    float s[8] = {0.f, 0.f, 0.f, 0.f, 0.f, 0.f, 0.f, 0.f};
#pragma unroll
    for (int a2 = 0; a2 < A_; ++a2) {
      const u16x8 v = *reinterpret_cast<const u16x8*>(
          pwb + ((size_t)a2 * ROWS + r0) * F_ + i);
#pragma unroll
      for (int j = 0; j < 8; ++j) s[j] += bf2f(v[j]);
    }
    u16x8 o;
#pragma unroll
    for (int j = 0; j < 8; ++j) o[j] = f2bf(s[j]);
    *reinterpret_cast<u16x8*>(&S2[TIL * F_ + i]) = o;
  }
  __syncthreads();

  const int lane = tid & 63, wv = tid >> 6;
  const int arow = lane & 15, kg = lane >> 4;
  const unsigned short* __restrict__ Wp = w12 + (size_t)a * KS2 * NTL * 512;
  f32x4 acc[2][2];
#pragma unroll
  for (int c = 0; c < 2; ++c)
#pragma unroll
    for (int mb = 0; mb < 2; ++mb) acc[c][mb] = (f32x4){0.f, 0.f, 0.f, 0.f};
  const int ssw = (arow & 7) << 3;
#pragma unroll
  for (int t = 0; t < KS2; ++t) {
    const int half = t >> 3;              // t<8: pw, t>=8: mutual
    const int kk   = (t & 7) * 32;
    bf16x8 af[2];
#pragma unroll
    for (int mb = 0; mb < 2; ++mb) {
      const int si = half * (TIL * F_) + (mb * 16 + arow) * F_ + ((kk + kg * 8) ^ ssw);
      af[mb] = *reinterpret_cast<const bf16x8*>(&S2[si]);
    }
#pragma unroll
    for (int c = 0; c < 2; ++c) {
      const int nt = wv * 2 + c;
      const bf16x8 bfr = *reinterpret_cast<const bf16x8*>(
          Wp + ((size_t)(t * NTL + nt) * 64 + lane) * 8);
#pragma unroll
      for (int mb = 0; mb < 2; ++mb)
        acc[c][mb] = __builtin_amdgcn_mfma_f32_16x16x32_bf16(af[mb], bfr, acc[c][mb], 0, 0, 0);
    }
  }

#pragma unroll
  for (int c = 0; c < 2; ++c) {
    const int col = (wv * 2 + c) * 16 + arow;
    const float bb2 = b2[a * F_ + col];
#pragma unroll
    for (int mb = 0; mb < 2; ++mb) {
#pragma unroll
      for (int rr = 0; rr < 4; ++rr) {
        const int row = mb * 16 + kg * 4 + rr;
        const int r   = r0 + row;
        if (r < RTOT) {
          const int bb = r / N_, n = r - bb * N_;
          const size_t o = ((size_t)(bb * A_ + a) * N_ + n) * F_ + col;
          out[o] = fmaxf(acc[c][mb][rr] + bb2, 0.f) + nf[o];
        }
      }
    }
  }
}

// ---------------------------------------------------------------------------
extern "C" void kernel_launch(void* const* d_in, const int* in_sizes, int n_in,
                              void* d_out, int out_size, void* d_ws, size_t ws_size,
                              hipStream_t stream)
{
  const float* nf     = (const float*)d_in[0];
  const int*   nn_idx = (const int*)  d_in[1];
  const int*   et     = (const int*)  d_in[2];
  const float* W      = (const float*)d_in[3];
  const float* bias   = (const float*)d_in[4];
  const float* W1     = (const float*)d_in[5];
  const float* W2     = (const float*)d_in[6];
  const float* b2     = (const float*)d_in[7];
  float* out = (float*)d_out;

  unsigned short* wpk  = (unsigned short*)d_ws;
  unsigned short* w12  = (unsigned short*)((char*)d_ws + OFF_W12);
  unsigned short* pwb  = (unsigned short*)((char*)d_ws + OFF_PWB);
  unsigned short* Sg   = (unsigned short*)((char*)d_ws + OFF_SG);
  float*          CNTS = (float*)((char*)d_ws + OFF_CNT);

  k_gather_pack<<<dim3(GATHER_BLOCKS + PACK_BLOCKS), 256, 0, stream>>>(
      nf, nn_idx, et, W, W1, W2, Sg, CNTS, wpk, w12);

  k_gemm1<<<dim3(GBL), 512, 0, stream>>>(Sg, CNTS, wpk, bias, pwb);
  k_hop_mfma<<<dim3(GBL), 512, 0, stream>>>(pwb, w12, b2, nf, out);
}